// Round 9
// baseline (52.940 us; speedup 1.0000x reference)
//
#include <hip/hip_runtime.h>

#define NBINS 15
#define NBLK  1024   // 4 blocks/CU on 256 CUs; 16 float4-tiles per thread

typedef float f4 __attribute__((ext_vector_type(4)));
typedef int   i4 __attribute__((ext_vector_type(4)));

// ---- inline-asm load / counted-wait primitives (compiler cannot sink these) ----
#define GLD_F4(dst, p) asm volatile("global_load_dwordx4 %0, %1, off" : "=v"(dst) : "v"(p))
#define GLD_I4(dst, p) asm volatile("global_load_dwordx4 %0, %1, off" : "=v"(dst) : "v"(p))
// Counted wait: N loads may stay in flight. sched_barrier(0) right after keeps
// the dependent VALU from being hoisted above the wait (guide rule #18).
#define WAITV(n)                                                                \
    do {                                                                        \
        asm volatile("s_waitcnt vmcnt(" #n ")" ::: "memory");                   \
        __builtin_amdgcn_sched_barrier(0);                                      \
    } while (0)

// Per-element update on NAMED scalar accumulators (VGPR-resident).
// bin k covers (k/15,(k+1)/15] -> ceilf(cv*15) == k+1 (float compare, no cvt).
// cv<=0 -> ceil<=0 matches nothing; uniform(0,1) -> ceil<=15. d = cv-(pred==lab).
#define ECE_ELEM(cv_, pr_, lb_)                                                 \
    do {                                                                        \
        float cv = (cv_);                                                       \
        float bf = ceilf(cv * 15.0f);                                           \
        float d = cv - (((pr_) == (lb_)) ? 1.0f : 0.0f);                        \
        a0  += (bf == 1.0f)  ? d : 0.0f;  a1  += (bf == 2.0f)  ? d : 0.0f;      \
        a2  += (bf == 3.0f)  ? d : 0.0f;  a3  += (bf == 4.0f)  ? d : 0.0f;      \
        a4  += (bf == 5.0f)  ? d : 0.0f;  a5  += (bf == 6.0f)  ? d : 0.0f;      \
        a6  += (bf == 7.0f)  ? d : 0.0f;  a7  += (bf == 8.0f)  ? d : 0.0f;      \
        a8  += (bf == 9.0f)  ? d : 0.0f;  a9  += (bf == 10.0f) ? d : 0.0f;      \
        a10 += (bf == 11.0f) ? d : 0.0f;  a11 += (bf == 12.0f) ? d : 0.0f;      \
        a12 += (bf == 13.0f) ? d : 0.0f;  a13 += (bf == 14.0f) ? d : 0.0f;      \
        a14 += (bf == 15.0f) ? d : 0.0f;                                        \
    } while (0)

#define ECE_TILE(c, p, l)                                                       \
    do {                                                                        \
        ECE_ELEM((c).x, (p).x, (l).x); ECE_ELEM((c).y, (p).y, (l).y);           \
        ECE_ELEM((c).z, (p).z, (l).z); ECE_ELEM((c).w, (p).w, (l).w);           \
    } while (0)

// Issue one phase's 6 loads (2 tiles x {conf,pred,lab}) and advance cursors.
#define PHASE_LOAD(C0, P0, L0, C1, P1, L1)                                      \
    do {                                                                        \
        GLD_F4(C0, cl);          GLD_F4(C1, cl + stride);                       \
        GLD_I4(P0, pl);          GLD_I4(P1, pl + stride);                       \
        GLD_I4(L0, ll);          GLD_I4(L1, ll + stride);                       \
        cl += 2 * stride; pl += 2 * stride; ll += 2 * stride;                   \
    } while (0)

#define WAVE_RED(A)                                                             \
    do {                                                                        \
        A += __shfl_xor(A, 1, 64);  A += __shfl_xor(A, 2, 64);                  \
        A += __shfl_xor(A, 4, 64);  A += __shfl_xor(A, 8, 64);                  \
        A += __shfl_xor(A, 16, 64); A += __shfl_xor(A, 32, 64);                 \
    } while (0)

__global__ __launch_bounds__(256) void ece_main(const float* __restrict__ conf,
                                                const int* __restrict__ pred,
                                                const int* __restrict__ lab,
                                                float* __restrict__ ws,
                                                int nvec) {
    float a0 = 0.0f, a1 = 0.0f, a2 = 0.0f, a3 = 0.0f, a4 = 0.0f;
    float a5 = 0.0f, a6 = 0.0f, a7 = 0.0f, a8 = 0.0f, a9 = 0.0f;
    float a10 = 0.0f, a11 = 0.0f, a12 = 0.0f, a13 = 0.0f, a14 = 0.0f;

    const int tid    = blockIdx.x * blockDim.x + threadIdx.x;
    const int stride = gridDim.x * blockDim.x;

    bool pipe  = (nvec % stride) == 0;
    int  niter = pipe ? (nvec / stride) : 0;     // tiles per thread (16 expected)
    if (niter < 4 || (niter & 3)) pipe = false;  // need multiple of 4 phases*2

    if (pipe) {
        const f4* cl = (const f4*)conf + tid;
        const i4* pl = (const i4*)pred + tid;
        const i4* ll = (const i4*)lab  + tid;

        f4 cX0, cX1, cY0, cY1;
        i4 pX0, pX1, pY0, pY1, lX0, lX1, lY0, lY1;

        // Prefill: phase 0's data -> set X. 6 loads in flight.
        PHASE_LOAD(cX0, pX0, lX0, cX1, pX1, lX1);

        const int nphase = niter >> 1;           // 8 phases of 2 tiles
        // Steady state: issue next phase's 6 loads, wait for the previous 6
        // (vmcnt(6): the just-issued batch stays in flight), compute.
        for (int ph = 0; ph + 2 < nphase; ph += 2) {
            PHASE_LOAD(cY0, pY0, lY0, cY1, pY1, lY1);
            WAITV(6);
            ECE_TILE(cX0, pX0, lX0); ECE_TILE(cX1, pX1, lX1);

            PHASE_LOAD(cX0, pX0, lX0, cX1, pX1, lX1);
            WAITV(6);
            ECE_TILE(cY0, pY0, lY0); ECE_TILE(cY1, pY1, lY1);
        }
        // Phase nphase-2: load last pair -> Y, compute X.
        PHASE_LOAD(cY0, pY0, lY0, cY1, pY1, lY1);
        WAITV(6);
        ECE_TILE(cX0, pX0, lX0); ECE_TILE(cX1, pX1, lX1);
        // Final phase: drain and compute Y.
        WAITV(0);
        ECE_TILE(cY0, pY0, lY0); ECE_TILE(cY1, pY1, lY1);
    } else {
        // Generic fallback (any shape).
        const f4* c4 = (const f4*)conf;
        const i4* p4 = (const i4*)pred;
        const i4* l4 = (const i4*)lab;
        for (int i = tid; i < nvec; i += stride) {
            f4 c = c4[i]; i4 p = p4[i]; i4 l = l4[i];
            ECE_TILE(c, p, l);
        }
    }

    // Wave-level butterfly reduction (64 lanes) per bin.
    WAVE_RED(a0);  WAVE_RED(a1);  WAVE_RED(a2);  WAVE_RED(a3);  WAVE_RED(a4);
    WAVE_RED(a5);  WAVE_RED(a6);  WAVE_RED(a7);  WAVE_RED(a8);  WAVE_RED(a9);
    WAVE_RED(a10); WAVE_RED(a11); WAVE_RED(a12); WAVE_RED(a13); WAVE_RED(a14);

    // Block partials via LDS; plain store to a per-block slot (no init kernel,
    // no global atomics, no device fence -> R2-R4's ~330us fence cost avoided).
    __shared__ float s_h[4][16];
    int wave = threadIdx.x >> 6;
    int lane = threadIdx.x & 63;
    if (lane == 0) {
        s_h[wave][0]  = a0;  s_h[wave][1]  = a1;  s_h[wave][2]  = a2;
        s_h[wave][3]  = a3;  s_h[wave][4]  = a4;  s_h[wave][5]  = a5;
        s_h[wave][6]  = a6;  s_h[wave][7]  = a7;  s_h[wave][8]  = a8;
        s_h[wave][9]  = a9;  s_h[wave][10] = a10; s_h[wave][11] = a11;
        s_h[wave][12] = a12; s_h[wave][13] = a13; s_h[wave][14] = a14;
    }
    __syncthreads();
    if (threadIdx.x < NBINS) {
        int k = threadIdx.x;
        // Transposed layout ws[k*NBLK + block] -> coalesced reads in ece_final.
        ws[k * NBLK + blockIdx.x] =
            s_h[0][k] + s_h[1][k] + s_h[2][k] + s_h[3][k];
    }
}

__global__ __launch_bounds__(256) void ece_final(const float* __restrict__ ws,
                                                 float* __restrict__ out,
                                                 float inv_n) {
    __shared__ float s_f[16];
    int t   = threadIdx.x;
    int bin = t >> 4;
    int idx = t & 15;
    float p = 0.0f;
    if (t < 240) {
        const float* row = ws + bin * NBLK;
        for (int j = idx; j < NBLK; j += 16) p += row[j];
    }
    p += __shfl_xor(p, 1, 64); p += __shfl_xor(p, 2, 64);
    p += __shfl_xor(p, 4, 64); p += __shfl_xor(p, 8, 64);
    if (t < 240 && idx == 0) s_f[bin] = p;
    __syncthreads();

    float v = 0.0f;
    if (t < NBINS) v = fabsf(s_f[t]) * inv_n;
    WAVE_RED(v);
    if (t == 0) out[0] = v;
}

extern "C" void kernel_launch(void* const* d_in, const int* in_sizes, int n_in,
                              void* d_out, int out_size, void* d_ws, size_t ws_size,
                              hipStream_t stream) {
    const float* conf = (const float*)d_in[0];
    const int*   pred = (const int*)d_in[1];
    const int*   lab  = (const int*)d_in[2];
    float* ws  = (float*)d_ws;
    float* out = (float*)d_out;
    int n    = in_sizes[0];
    int nvec = n / 4;        // N = 16777216, divisible by 4

    ece_main<<<NBLK, 256, 0, stream>>>(conf, pred, lab, ws, nvec);
    ece_final<<<1, 256, 0, stream>>>(ws, out, 1.0f / (float)n);
}